// Round 7
// baseline (201.538 us; speedup 1.0000x reference)
//
#include <hip/hip_runtime.h>
#include <hip/hip_bf16.h>

#define B_N     2048
#define IN_N    512
#define SEQ_N   128
#define HID_N   12
#define HP_N    16
#define OUT_N   3
#define CSTF    524   // f32 C row stride in dwords; h*524%32 = h*12%32 spreads banks
#define CSTB    520   // bf16 C row stride (ushorts): 1040B rows, 16B-aligned

typedef __attribute__((ext_vector_type(8))) short short8;
typedef __attribute__((ext_vector_type(4))) float f32x4;
typedef unsigned int uint;
typedef unsigned short ushort;

__device__ __forceinline__ float fast_tanh(float x) {
    float e = __builtin_amdgcn_exp2f(x * 2.8853900817779268f);
    return 1.0f - 2.0f * __builtin_amdgcn_rcpf(e + 1.0f);
}

__device__ __forceinline__ ushort f2bf(float f) {   // RNE fp32->bf16
    uint u = __float_as_uint(f);
    u += 0x7fffu + ((u >> 16) & 1u);
    return (ushort)(u >> 16);
}

__device__ __forceinline__ float bf2f(ushort s) {
    return __uint_as_float(((uint)s) << 16);
}

// DPP quad-broadcast: every lane in a quad gets lane (quad_base + Q)'s value.
template<int Q>
__device__ __forceinline__ float qbcast(float v) {
    return __int_as_float(__builtin_amdgcn_update_dpp(
        0, __float_as_int(v), Q * 0x55, 0xf, 0xf, true));
}
__device__ __forceinline__ void qgather(float src, float* d) {
    d[0] = qbcast<0>(src); d[1] = qbcast<1>(src);
    d[2] = qbcast<2>(src); d[3] = qbcast<3>(src);
}

// Raw HW LDS float add (HIP atomicAdd on LDS floats expands to a CAS loop
// without -munsafe-fp-atomics; ds_add_f32 is the single-instruction form).
// addr = LDS byte offset (low 32 bits of the flat pointer: LDS aperture is
// 4GB-aligned). 12 adds, one per h row, immediate offsets h*CSTF*4.
#define SCATTER12(A, W)                                                        \
    asm volatile(                                                              \
        "ds_add_f32 %0, %1 offset:0\n\t"                                       \
        "ds_add_f32 %0, %2 offset:2096\n\t"                                    \
        "ds_add_f32 %0, %3 offset:4192\n\t"                                    \
        "ds_add_f32 %0, %4 offset:6288\n\t"                                    \
        "ds_add_f32 %0, %5 offset:8384\n\t"                                    \
        "ds_add_f32 %0, %6 offset:10480\n\t"                                   \
        "ds_add_f32 %0, %7 offset:12576\n\t"                                   \
        "ds_add_f32 %0, %8 offset:14672\n\t"                                   \
        "ds_add_f32 %0, %9 offset:16768\n\t"                                   \
        "ds_add_f32 %0, %10 offset:18864\n\t"                                  \
        "ds_add_f32 %0, %11 offset:20960\n\t"                                  \
        "ds_add_f32 %0, %12 offset:23056"                                      \
        :: "v"(A), "v"(W[0]), "v"(W[1]), "v"(W[2]), "v"(W[3]), "v"(W[4]),      \
           "v"(W[5]), "v"(W[6]), "v"(W[7]), "v"(W[8]), "v"(W[9]), "v"(W[10]),  \
           "v"(W[11]) : "memory")

// ---------------------------------------------------------------------------
// k_prep: pack embT (128 s x 512 r) into MFMA A-fragment order (bf16).
// Frag f = t8*16 + ks covers s in [t8*16,+16), r in [ks*32,+32).
// Lane l holds A[m=l&15][k=(l>>4)*8+j] = emb[r0+j][s], uint4-packed.
// ---------------------------------------------------------------------------
__global__ __launch_bounds__(64) void k_prep(
    const float* __restrict__ emb, ushort* __restrict__ embF)
{
    const int f  = blockIdx.x;          // 0..127
    const int l  = threadIdx.x;
    const int t8 = f >> 4, ks = f & 15;
    const int s  = t8 * 16 + (l & 15);
    const int r0 = ks * 32 + (l >> 4) * 8;
    ushort v[8];
    #pragma unroll
    for (int j = 0; j < 8; ++j)
        v[j] = f2bf(emb[(r0 + j) * SEQ_N + s]);
    uint4 o;
    o.x = (uint)v[0] | ((uint)v[1] << 16);
    o.y = (uint)v[2] | ((uint)v[3] << 16);
    o.z = (uint)v[4] | ((uint)v[5] << 16);
    o.w = (uint)v[6] | ((uint)v[7] << 16);
    ((uint4*)embF)[f * 64 + l] = o;
}

// ---------------------------------------------------------------------------
// k_fused: one block (256 thr) per batch. Everything after prep in 1 launch:
//  P0 zero U/revAcc, load x pair + w rows (coalesced), issue rev gathers
//  P1 scatter C_b[h][r] += w_ih_f[h][i] via ds_add_f32 (HW LDS fp atomics)
//  P2 cvt C -> bf16; rev partial + wave-reduce + ds_add into revAcc
//  P3 MFMA: A-frags stream from embF (global), B-frags ds_read_b128 from Cb;
//     pre tile -> LDS preS (no global round-trip). waves 1-3 exit.
//  P4 wave 0: tanh(revAcc) -> hrevS; 128-step DPP scan on preS; FC; store.
// ---------------------------------------------------------------------------
__global__ __launch_bounds__(256) void k_fused(
    const int* __restrict__ x, const ushort* __restrict__ embF,
    const float* __restrict__ emb,
    const float* __restrict__ w_ih_f, const float* __restrict__ w_ih_r,
    const float* __restrict__ b_ih_f, const float* __restrict__ b_hh_f,
    const float* __restrict__ b_ih_r, const float* __restrict__ b_hh_r,
    const float* __restrict__ w_hh_f,
    const float* __restrict__ fc_w, const float* __restrict__ fc_b,
    float* __restrict__ out)
{
    __shared__ __align__(16) float U[12 * CSTF];      // 25.2 KB, reused as Cb
    __shared__ __align__(16) ushort preS[SEQ_N * HP_N];  // 4 KB
    __shared__ float revAcc[12];
    __shared__ float hrevS[12];
    ushort* Cb = (ushort*)U;

    const int t    = threadIdx.x;
    const int b    = blockIdx.x;
    const int w    = t >> 6;
    const int l    = t & 63;
    const int h16  = l & 15;
    const int quad = l >> 4;

    // P0: loads + zero
    const int2 xi = ((const int2*)(x + b * IN_N))[t];   // i = 2t, 2t+1
    const float ev0 = emb[(size_t)xi.x * SEQ_N + 127];  // rev gathers (early)
    const float ev1 = emb[(size_t)xi.y * SEQ_N + 127];

    float wf0[12], wf1[12];
    #pragma unroll
    for (int h = 0; h < 12; ++h) {
        float2 p = *(const float2*)(w_ih_f + h * IN_N + 2 * t);
        wf0[h] = p.x; wf1[h] = p.y;
    }

    float4 z4 = make_float4(0.f, 0.f, 0.f, 0.f);
    for (int idx = t; idx < (12 * CSTF) / 4; idx += 256)
        ((float4*)U)[idx] = z4;
    if (t < 12) revAcc[t] = 0.f;
    __syncthreads();

    // P1: scatter
    const uint ubase = (uint)(uintptr_t)&U[0];
    SCATTER12(ubase + (uint)xi.x * 4u, wf0);
    SCATTER12(ubase + (uint)xi.y * 4u, wf1);
    __syncthreads();

    // P2a: rev partials (VALU + small loads) while LDS settles
    float pr[12];
    #pragma unroll
    for (int h = 0; h < 12; ++h) {
        float2 p = *(const float2*)(w_ih_r + h * IN_N + 2 * t);
        pr[h] = __builtin_fmaf(ev0, p.x, ev1 * p.y);
    }
    #pragma unroll
    for (int off = 32; off; off >>= 1)
        #pragma unroll
        for (int h = 0; h < 12; ++h) pr[h] += __shfl_xor(pr[h], off);
    if (l == 0) {
        const uint rbase = (uint)(uintptr_t)&revAcc[0];
        asm volatile(
            "ds_add_f32 %0, %1 offset:0\n\t"
            "ds_add_f32 %0, %2 offset:4\n\t"
            "ds_add_f32 %0, %3 offset:8\n\t"
            "ds_add_f32 %0, %4 offset:12\n\t"
            "ds_add_f32 %0, %5 offset:16\n\t"
            "ds_add_f32 %0, %6 offset:20\n\t"
            "ds_add_f32 %0, %7 offset:24\n\t"
            "ds_add_f32 %0, %8 offset:28\n\t"
            "ds_add_f32 %0, %9 offset:32\n\t"
            "ds_add_f32 %0, %10 offset:36\n\t"
            "ds_add_f32 %0, %11 offset:40\n\t"
            "ds_add_f32 %0, %12 offset:44"
            :: "v"(rbase), "v"(pr[0]), "v"(pr[1]), "v"(pr[2]), "v"(pr[3]),
               "v"(pr[4]), "v"(pr[5]), "v"(pr[6]), "v"(pr[7]), "v"(pr[8]),
               "v"(pr[9]), "v"(pr[10]), "v"(pr[11]) : "memory");
    }

    // P2b: cvt f32 C -> bf16 Cb in place (regs + barrier)
    float tmp[24];
    #pragma unroll
    for (int h = 0; h < 12; ++h) {
        tmp[2 * h]     = U[h * CSTF + t];
        tmp[2 * h + 1] = U[h * CSTF + 256 + t];
    }
    __syncthreads();
    #pragma unroll
    for (int h = 0; h < 12; ++h) {
        Cb[h * CSTB + t]       = f2bf(tmp[2 * h]);
        Cb[h * CSTB + 256 + t] = f2bf(tmp[2 * h + 1]);
    }
    __syncthreads();
    // Cb rows 12..15: stale garbage -> feeds D cols >=12 only (never read).

    // P3: MFMA. Wave w computes s-tiles 2w, 2w+1.
    const uint4* eF = (const uint4*)embF;
    f32x4 acc0 = {0.f, 0.f, 0.f, 0.f}, acc1 = {0.f, 0.f, 0.f, 0.f};
    #pragma unroll
    for (int ks = 0; ks < 16; ++ks) {
        union { uint4 u; short8 s; } a0, a1, bv;
        a0.u = eF[((w * 2 + 0) * 16 + ks) * 64 + l];
        a1.u = eF[((w * 2 + 1) * 16 + ks) * 64 + l];
        bv.u = *(const uint4*)&Cb[h16 * CSTB + ks * 32 + quad * 8];
        acc0 = __builtin_amdgcn_mfma_f32_16x16x32_bf16(a0.s, bv.s, acc0, 0, 0, 0);
        acc1 = __builtin_amdgcn_mfma_f32_16x16x32_bf16(a1.s, bv.s, acc1, 0, 0, 0);
    }
    // D: col=h16, row=quad*4+reg. Store to LDS preS[s][h16] (pads harmless).
    #pragma unroll
    for (int tt = 0; tt < 2; ++tt) {
        const f32x4 acc = tt ? acc1 : acc0;
        #pragma unroll
        for (int r = 0; r < 4; ++r) {
            int s = (w * 2 + tt) * 16 + quad * 4 + r;
            preS[s * HP_N + h16] = f2bf(acc[r]);
        }
    }
    __syncthreads();
    if (w != 0) return;          // waves 1-3 done; wave 0 runs the scan

    // P4: reverse hidden
    if (l < 12) hrevS[l] = fast_tanh(revAcc[l] + b_ih_r[l] + b_hh_r[l]);

    // scan setup: all 64 lanes run redundantly (quads identical); q = l&3
    const int q = l & 3;
    float W[3][12], bias[3];
    #pragma unroll
    for (int r = 0; r < 3; ++r) {
        int j = q + 4 * r;
        #pragma unroll
        for (int k = 0; k < 12; ++k) W[r][k] = w_hh_f[j * 12 + k];
        bias[r] = b_ih_f[j] + b_hh_f[j];
    }

    // pre pipeline: lane reads preS[s][q + 4r]
    float pc[3], pn[3];
    #pragma unroll
    for (int r = 0; r < 3; ++r) {
        pc[r] = bf2f(preS[0 * HP_N + q + 4 * r]) + bias[r];
        pn[r] = bf2f(preS[1 * HP_N + q + 4 * r]) + bias[r];
    }

    float hreg[3] = {0.f, 0.f, 0.f};
    for (int s = 0; s < SEQ_N; ++s) {
        int sp = (s + 2 < SEQ_N) ? s + 2 : SEQ_N - 1;
        float pf[3];
        #pragma unroll
        for (int r = 0; r < 3; ++r)
            pf[r] = bf2f(preS[sp * HP_N + q + 4 * r]) + bias[r];

        float hk[12];
        qgather(hreg[0], hk);
        qgather(hreg[1], hk + 4);
        qgather(hreg[2], hk + 8);

        #pragma unroll
        for (int r = 0; r < 3; ++r) {
            float a0 = pc[r], a1 = 0.f, a2 = 0.f;
            #pragma unroll
            for (int k = 0; k < 4; ++k) {
                a0 = __builtin_fmaf(W[r][k],     hk[k],     a0);
                a1 = __builtin_fmaf(W[r][k + 4], hk[k + 4], a1);
                a2 = __builtin_fmaf(W[r][k + 8], hk[k + 8], a2);
            }
            hreg[r] = fast_tanh(a0 + a1 + a2);
        }
        pc[0] = pn[0]; pc[1] = pn[1]; pc[2] = pn[2];
        pn[0] = pf[0]; pn[1] = pf[1]; pn[2] = pf[2];
    }

    // FC epilogue: lanes 0..2 (q==l) compute outputs
    float hk[12];
    qgather(hreg[0], hk);
    qgather(hreg[1], hk + 4);
    qgather(hreg[2], hk + 8);
    if (l < OUT_N) {
        const float* fw = fc_w + l * 24;
        float o = fc_b[l];
        #pragma unroll
        for (int k = 0; k < 12; ++k)
            o += fw[k] * hk[k] + fw[12 + k] * hrevS[k];
        out[b * OUT_N + l] = o;
    }
}

// ---------------------------------------------------------------------------
extern "C" void kernel_launch(void* const* d_in, const int* in_sizes, int n_in,
                              void* d_out, int out_size, void* d_ws, size_t ws_size,
                              hipStream_t stream) {
    const int*   x      = (const int*)  d_in[0];
    const float* emb    = (const float*)d_in[1];
    const float* w_ih_f = (const float*)d_in[2];
    const float* w_hh_f = (const float*)d_in[3];
    const float* b_ih_f = (const float*)d_in[4];
    const float* b_hh_f = (const float*)d_in[5];
    const float* w_ih_r = (const float*)d_in[6];
    const float* b_ih_r = (const float*)d_in[8];
    const float* b_hh_r = (const float*)d_in[9];
    const float* fc_w   = (const float*)d_in[10];
    const float* fc_b   = (const float*)d_in[11];
    float* out = (float*)d_out;

    ushort* embF = (ushort*)d_ws;    // 128 KB A-fragment pack

    k_prep <<<128, 64, 0, stream>>>(emb, embF);
    k_fused<<<B_N, 256, 0, stream>>>(x, embF, emb, w_ih_f, w_ih_r,
                                     b_ih_f, b_hh_f, b_ih_r, b_hh_r,
                                     w_hh_f, fc_w, fc_b, out);
}